// Round 7
// baseline (42.537 us; speedup 1.0000x reference)
//
#include <hip/hip_runtime.h>
#include <cmath>

// Problem constants (match the reference)
#define HH 256
#define WW 256
#define NG 1024
#define NB 2
static constexpr float FXc = 300.0f;
static constexpr float FYc = 300.0f;
static constexpr float CXc = 128.0f;
static constexpr float CYc = 128.0f;
static constexpr float EPSc = 1e-8f;
static constexpr float LOG2E = 1.4426950408889634f;

#if defined(__has_builtin)
#if __has_builtin(__builtin_amdgcn_exp2f)
#define FAST_EXP2(x) __builtin_amdgcn_exp2f(x)
#else
#define FAST_EXP2(x) exp2f(x)
#endif
#else
#define FAST_EXP2(x) exp2f(x)
#endif

// Two-kernel structure:
//   prep_kernel  <<<NB, 512>>> : project all gaussians once per batch into
//     d_ws as two float4 arrays: w0[b*NG+g]=(k,kx,ky,A), w1[b*NG+g]=(r,g,b,0).
//   render_kernel <<<2048, 256>>>: NO LDS, NO barrier. Thread = (quad,h):
//     2x2 pixel quad, 16-way gaussian split (g = i*16+h, 64 iters),
//     params read from global (L1-resident: 32KB/batch). Butterfly combine
//     over the 16-lane group, lanes h<4 write the quad's 4 pixels.
//   Occupancy: 2048 blocks = 8 blocks/CU, no LDS -> 32 waves/CU possible.
//   Per gaussian-quad: 3 exp (w00, Ex=2^d10, Ey=2^d01) + 3 mul; deltas
//   clamped <=126 so flushed far gaussians never make 0*inf (lossless:
//   slope at any non-flushed weight < 3.8 log2/px since |k|<=0.029).
__global__ __launch_bounds__(512) void prep_kernel(
    const float* __restrict__ positions,   // [N,3]
    const float* __restrict__ colors,      // [N,3]
    const float* __restrict__ opacities,   // [N,1]
    const float* __restrict__ scales,      // [N,1]
    const float* __restrict__ qvec,        // [B,4]
    const float* __restrict__ tvec,        // [B,3]
    float4* __restrict__ w0,               // [B*NG]
    float4* __restrict__ w1)               // [B*NG]
{
    const int b = blockIdx.x;
    float qw = qvec[b * 4 + 0], qx = qvec[b * 4 + 1];
    float qy = qvec[b * 4 + 2], qz = qvec[b * 4 + 3];
    float rin = rsqrtf(qw * qw + qx * qx + qy * qy + qz * qz);
    qw *= rin; qx *= rin; qy *= rin; qz *= rin;
    const float r00 = 1.0f - 2.0f * (qy * qy + qz * qz);
    const float r01 = 2.0f * (qx * qy - qz * qw);
    const float r02 = 2.0f * (qx * qz + qy * qw);
    const float r10 = 2.0f * (qx * qy + qz * qw);
    const float r11 = 1.0f - 2.0f * (qx * qx + qz * qz);
    const float r12 = 2.0f * (qy * qz - qx * qw);
    const float r20 = 2.0f * (qx * qz - qy * qw);
    const float r21 = 2.0f * (qy * qz + qx * qw);
    const float r22 = 1.0f - 2.0f * (qx * qx + qy * qy);
    const float t0 = tvec[b * 3 + 0], t1 = tvec[b * 3 + 1], t2 = tvec[b * 3 + 2];

    #pragma unroll
    for (int j = 0; j < NG / 512; ++j) {
        const int g = threadIdx.x + j * 512;
        const float X = positions[g * 3 + 0];
        const float Y = positions[g * 3 + 1];
        const float Z = positions[g * 3 + 2];
        const float cxp = r00 * X + r01 * Y + r02 * Z + t0;
        const float cyp = r10 * X + r11 * Y + r12 * Z + t1;
        const float czp = r20 * X + r21 * Y + r22 * Z + t2;
        const float iz = 1.0f / czp;
        const float ux = cxp * iz * FXc + CXc;
        const float uy = cyp * iz * FYc + CYc;
        const float s = scales[g];
        const float k = -0.5f * LOG2E / (s * s);
        const float lop = __log2f(opacities[g]);
        const float kx = -2.0f * k * ux;
        const float ky = -2.0f * k * uy;
        const float A = fmaf(k, fmaf(ux, ux, uy * uy), lop);
        w0[b * NG + g] = make_float4(k, kx, ky, A);
        w1[b * NG + g] = make_float4(colors[g * 3 + 0], colors[g * 3 + 1],
                                     colors[g * 3 + 2], 0.0f);
    }
}

__global__ __launch_bounds__(256, 8) void render_kernel(
    const float4* __restrict__ w0,         // [B*NG] (k,kx,ky,A)
    const float4* __restrict__ w1,         // [B*NG] (r,g,b,0)
    float* __restrict__ out)               // [B,3,H,W]
{
    const int b = blockIdx.x >> 10;         // 1024 blocks per batch
    const int tile = blockIdx.x & 1023;     // 64 px per block: 32x2 tile
    const int x0 = (tile & 7) << 5;         // 8 tiles of 32 px in x
    const int y0 = (tile >> 3) << 1;        // 128 tiles of 2 px in y

    const int h = threadIdx.x & 15;         // gaussian split lane
    const int t = threadIdx.x >> 4;         // quad id [0,16)
    const int px0i = x0 + (t << 1);         // 16 quads along x
    const int py0i = y0;
    const float px = (float)px0i;
    const float py = (float)py0i;
    const float c2 = fmaf(px, px, py * py);
    const float u = fmaf(2.0f, px, 1.0f);   // c2(x+1)-c2(x)
    const float v = fmaf(2.0f, py, 1.0f);   // c2(y+1)-c2(y)

    const float4* __restrict__ g0p = w0 + b * NG + h;
    const float4* __restrict__ g1p = w1 + b * NG + h;

    // accumulators: component x=(0,0), y=(+1,0), z=(0,+1), w=(+1,+1)
    float4 aden = make_float4(0.f, 0.f, 0.f, 0.f);
    float4 ar = aden, ag = aden, ab = aden;

    #pragma unroll 2
    for (int i = 0; i < NG / 16; ++i) {
        const float4 g0 = g0p[i << 4];
        const float4 g1 = g1p[i << 4];
        const float k = g0.x;
        float e00 = fmaf(k, c2, g0.w);
        e00 = fmaf(g0.y, px, e00);
        e00 = fmaf(g0.z, py, e00);
        const float d10 = fminf(fmaf(k, u, g0.y), 126.0f);  // e(x+1)-e(x)
        const float d01 = fminf(fmaf(k, v, g0.z), 126.0f);  // e(y+1)-e(y)
        const float w00 = FAST_EXP2(e00);
        const float Ex = FAST_EXP2(d10);
        const float Ey = FAST_EXP2(d01);
        const float w10 = w00 * Ex;
        const float w01 = w00 * Ey;
        const float w11 = w10 * Ey;
        aden.x += w00; aden.y += w10; aden.z += w01; aden.w += w11;
        ar.x = fmaf(w00, g1.x, ar.x); ar.y = fmaf(w10, g1.x, ar.y);
        ar.z = fmaf(w01, g1.x, ar.z); ar.w = fmaf(w11, g1.x, ar.w);
        ag.x = fmaf(w00, g1.y, ag.x); ag.y = fmaf(w10, g1.y, ag.y);
        ag.z = fmaf(w01, g1.y, ag.z); ag.w = fmaf(w11, g1.y, ag.w);
        ab.x = fmaf(w00, g1.z, ab.x); ab.y = fmaf(w10, g1.z, ab.y);
        ab.z = fmaf(w01, g1.z, ab.z); ab.w = fmaf(w11, g1.z, ab.w);
    }

    // --- butterfly combine across the 16-lane split group ---
    #pragma unroll
    for (int m = 1; m <= 8; m <<= 1) {
        aden.x += __shfl_xor(aden.x, m); aden.y += __shfl_xor(aden.y, m);
        aden.z += __shfl_xor(aden.z, m); aden.w += __shfl_xor(aden.w, m);
        ar.x += __shfl_xor(ar.x, m); ar.y += __shfl_xor(ar.y, m);
        ar.z += __shfl_xor(ar.z, m); ar.w += __shfl_xor(ar.w, m);
        ag.x += __shfl_xor(ag.x, m); ag.y += __shfl_xor(ag.y, m);
        ag.z += __shfl_xor(ag.z, m); ag.w += __shfl_xor(ag.w, m);
        ab.x += __shfl_xor(ab.x, m); ab.y += __shfl_xor(ab.y, m);
        ab.z += __shfl_xor(ab.z, m); ab.w += __shfl_xor(ab.w, m);
    }

    // --- epilogue: lanes h<4 each write one pixel of the quad ---
    if (h < 4) {
        float den, cr, cg, cb;
        if (h == 0)      { den = aden.x; cr = ar.x; cg = ag.x; cb = ab.x; }
        else if (h == 1) { den = aden.y; cr = ar.y; cg = ag.y; cb = ab.y; }
        else if (h == 2) { den = aden.z; cr = ar.z; cg = ag.z; cb = ab.z; }
        else             { den = aden.w; cr = ar.w; cg = ag.w; cb = ab.w; }
        const int pxx = px0i + (h & 1);
        const int pyy = py0i + (h >> 1);
        const float inv = 1.0f / (den + EPSc);
        const size_t o = (size_t)b * 3 * 65536 + (size_t)pyy * WW + pxx;
        out[o]           = cr * inv;
        out[o + 65536]   = cg * inv;
        out[o + 131072]  = cb * inv;
    }
}

extern "C" void kernel_launch(void* const* d_in, const int* in_sizes, int n_in,
                              void* d_out, int out_size, void* d_ws, size_t ws_size,
                              hipStream_t stream) {
    const float* positions = (const float*)d_in[0];
    const float* colors    = (const float*)d_in[1];
    const float* opacities = (const float*)d_in[2];
    const float* scales    = (const float*)d_in[3];
    const float* qvec      = (const float*)d_in[4];
    const float* tvec      = (const float*)d_in[5];
    float* out = (float*)d_out;

    float4* w0 = (float4*)d_ws;                 // NB*NG float4
    float4* w1 = ((float4*)d_ws) + NB * NG;     // NB*NG float4 (total 64 KB)

    prep_kernel<<<dim3(NB), dim3(512), 0, stream>>>(
        positions, colors, opacities, scales, qvec, tvec, w0, w1);
    render_kernel<<<dim3(NB * 1024), dim3(256), 0, stream>>>(w0, w1, out);
}

// Round 8
// 35.890 us; speedup vs baseline: 1.1852x; 1.1852x over previous
//
#include <hip/hip_runtime.h>
#include <cmath>

// Problem constants (match the reference)
#define HH 256
#define WW 256
#define NG 1024
#define NB 2
static constexpr float FXc = 300.0f;
static constexpr float FYc = 300.0f;
static constexpr float CXc = 128.0f;
static constexpr float CYc = 128.0f;
static constexpr float EPSc = 1e-8f;
static constexpr float LOG2E = 1.4426950408889634f;

#if defined(__has_builtin)
#if __has_builtin(__builtin_amdgcn_exp2f)
#define FAST_EXP2(x) __builtin_amdgcn_exp2f(x)
#else
#define FAST_EXP2(x) exp2f(x)
#endif
#else
#define FAST_EXP2(x) exp2f(x)
#endif

// Layout (R6 data path + 100% occupancy grid):
//   grid = 1024 blocks (NB * 512), 512 threads, 32x4-px tile per block.
//   Thread = (quad t [0,32), h [0,16)).  Each thread: 2x2 pixel quad,
//   gaussians g = i*16 + h (i in [0,64)) -> 16-way split, shfl_xor combine.
//   Occupancy: 512 thr + 32KB LDS -> 4 blocks/CU (thread-capped), grid
//   1024 = 4/CU exactly -> 32 waves/CU ceiling (needs VGPR<=64).
//   Per gaussian-quad: 3 exp (w00, Ex=2^d10, Ey=2^d01) + 3 mul; deltas
//   clamped <=126 so flushed far gaussians never make 0*inf (lossless:
//   slope at any non-flushed weight < 3.8 log2/px since |k|<=0.029).
//   LDS: split 16B-stride arrays; 16 h-addresses -> 2 distinct addrs per
//   bank-quad = free 2-way aliasing (m136).
__global__ __launch_bounds__(512) void render_kernel(
    const float* __restrict__ positions,   // [N,3]
    const float* __restrict__ colors,      // [N,3]
    const float* __restrict__ opacities,   // [N,1]
    const float* __restrict__ scales,      // [N,1]
    const float* __restrict__ qvec,        // [B,4]
    const float* __restrict__ tvec,        // [B,3]
    float* __restrict__ out)               // [B,3,H,W]
{
    __shared__ float4 gs0[NG];  // (k, kx, ky, A)  A = k*|u|^2 + log2(op)
    __shared__ float4 gs1[NG];  // (r, g, b, 0)

    const int b = blockIdx.x >> 9;          // 512 blocks per batch
    const int tile = blockIdx.x & 511;
    const int x0 = (tile & 7) << 5;         // 8 tiles of 32 px in x
    const int y0 = (tile >> 3) << 2;        // 64 tiles of 4 px in y

    // --- per-thread (wave-uniform) rotation setup ---
    float qw = qvec[b * 4 + 0], qx = qvec[b * 4 + 1];
    float qy = qvec[b * 4 + 2], qz = qvec[b * 4 + 3];
    float rin = rsqrtf(qw * qw + qx * qx + qy * qy + qz * qz);
    qw *= rin; qx *= rin; qy *= rin; qz *= rin;
    const float r00 = 1.0f - 2.0f * (qy * qy + qz * qz);
    const float r01 = 2.0f * (qx * qy - qz * qw);
    const float r02 = 2.0f * (qx * qz + qy * qw);
    const float r10 = 2.0f * (qx * qy + qz * qw);
    const float r11 = 1.0f - 2.0f * (qx * qx + qz * qz);
    const float r12 = 2.0f * (qy * qz - qx * qw);
    const float r20 = 2.0f * (qx * qz - qy * qw);
    const float r21 = 2.0f * (qy * qz + qx * qw);
    const float r22 = 1.0f - 2.0f * (qx * qx + qy * qy);
    const float t0 = tvec[b * 3 + 0], t1 = tvec[b * 3 + 1], t2 = tvec[b * 3 + 2];

    // --- stage all N gaussians into LDS (each thread projects 2) ---
    #pragma unroll
    for (int j = 0; j < NG / 512; ++j) {
        const int g = threadIdx.x + j * 512;
        const float X = positions[g * 3 + 0];
        const float Y = positions[g * 3 + 1];
        const float Z = positions[g * 3 + 2];
        const float cxp = r00 * X + r01 * Y + r02 * Z + t0;
        const float cyp = r10 * X + r11 * Y + r12 * Z + t1;
        const float czp = r20 * X + r21 * Y + r22 * Z + t2;
        const float iz = 1.0f / czp;
        const float ux = cxp * iz * FXc + CXc;
        const float uy = cyp * iz * FYc + CYc;
        const float s = scales[g];
        const float k = -0.5f * LOG2E / (s * s);
        const float lop = __log2f(opacities[g]);
        const float kx = -2.0f * k * ux;
        const float ky = -2.0f * k * uy;
        const float A = fmaf(k, fmaf(ux, ux, uy * uy), lop);
        gs0[g] = make_float4(k, kx, ky, A);
        gs1[g] = make_float4(colors[g * 3 + 0], colors[g * 3 + 1],
                             colors[g * 3 + 2], 0.0f);
    }
    __syncthreads();

    // --- quad / split decomposition ---
    const int h = threadIdx.x & 15;         // gaussian split lane [0,16)
    const int t = threadIdx.x >> 4;         // quad id [0,32)
    const int px0i = x0 + ((t & 15) << 1);  // 16 quads in x
    const int py0i = y0 + ((t >> 4) << 1);  // 2 quads in y
    const float px = (float)px0i;
    const float py = (float)py0i;
    const float c2 = fmaf(px, px, py * py);
    const float u = fmaf(2.0f, px, 1.0f);   // c2(x+1)-c2(x)
    const float v = fmaf(2.0f, py, 1.0f);   // c2(y+1)-c2(y)

    // accumulators: component x=(0,0), y=(+1,0), z=(0,+1), w=(+1,+1)
    float4 aden = make_float4(0.f, 0.f, 0.f, 0.f);
    float4 ar = aden, ag = aden, ab = aden;

    #pragma unroll 4
    for (int i = 0; i < NG / 16; ++i) {
        const int g = (i << 4) + h;
        const float4 g0 = gs0[g];
        const float4 g1 = gs1[g];
        const float k = g0.x;
        float e00 = fmaf(k, c2, g0.w);
        e00 = fmaf(g0.y, px, e00);
        e00 = fmaf(g0.z, py, e00);
        const float d10 = fminf(fmaf(k, u, g0.y), 126.0f);  // e(x+1)-e(x)
        const float d01 = fminf(fmaf(k, v, g0.z), 126.0f);  // e(y+1)-e(y)
        const float w00 = FAST_EXP2(e00);
        const float Ex = FAST_EXP2(d10);
        const float Ey = FAST_EXP2(d01);
        const float w10 = w00 * Ex;
        const float w01 = w00 * Ey;
        const float w11 = w10 * Ey;
        aden.x += w00; aden.y += w10; aden.z += w01; aden.w += w11;
        ar.x = fmaf(w00, g1.x, ar.x); ar.y = fmaf(w10, g1.x, ar.y);
        ar.z = fmaf(w01, g1.x, ar.z); ar.w = fmaf(w11, g1.x, ar.w);
        ag.x = fmaf(w00, g1.y, ag.x); ag.y = fmaf(w10, g1.y, ag.y);
        ag.z = fmaf(w01, g1.y, ag.z); ag.w = fmaf(w11, g1.y, ag.w);
        ab.x = fmaf(w00, g1.z, ab.x); ab.y = fmaf(w10, g1.z, ab.y);
        ab.z = fmaf(w01, g1.z, ab.z); ab.w = fmaf(w11, g1.z, ab.w);
    }

    // --- butterfly combine across the 16-lane split group ---
    #pragma unroll
    for (int m = 1; m <= 8; m <<= 1) {
        aden.x += __shfl_xor(aden.x, m); aden.y += __shfl_xor(aden.y, m);
        aden.z += __shfl_xor(aden.z, m); aden.w += __shfl_xor(aden.w, m);
        ar.x += __shfl_xor(ar.x, m); ar.y += __shfl_xor(ar.y, m);
        ar.z += __shfl_xor(ar.z, m); ar.w += __shfl_xor(ar.w, m);
        ag.x += __shfl_xor(ag.x, m); ag.y += __shfl_xor(ag.y, m);
        ag.z += __shfl_xor(ag.z, m); ag.w += __shfl_xor(ag.w, m);
        ab.x += __shfl_xor(ab.x, m); ab.y += __shfl_xor(ab.y, m);
        ab.z += __shfl_xor(ab.z, m); ab.w += __shfl_xor(ab.w, m);
    }

    // --- epilogue: lanes h<4 each write one pixel of the quad ---
    if (h < 4) {
        float den, cr, cg, cb;
        if (h == 0)      { den = aden.x; cr = ar.x; cg = ag.x; cb = ab.x; }
        else if (h == 1) { den = aden.y; cr = ar.y; cg = ag.y; cb = ab.y; }
        else if (h == 2) { den = aden.z; cr = ar.z; cg = ag.z; cb = ab.z; }
        else             { den = aden.w; cr = ar.w; cg = ag.w; cb = ab.w; }
        const int pxx = px0i + (h & 1);
        const int pyy = py0i + (h >> 1);
        const float inv = 1.0f / (den + EPSc);
        const size_t o = (size_t)b * 3 * 65536 + (size_t)pyy * WW + pxx;
        out[o]           = cr * inv;
        out[o + 65536]   = cg * inv;
        out[o + 131072]  = cb * inv;
    }
}

extern "C" void kernel_launch(void* const* d_in, const int* in_sizes, int n_in,
                              void* d_out, int out_size, void* d_ws, size_t ws_size,
                              hipStream_t stream) {
    const float* positions = (const float*)d_in[0];
    const float* colors    = (const float*)d_in[1];
    const float* opacities = (const float*)d_in[2];
    const float* scales    = (const float*)d_in[3];
    const float* qvec      = (const float*)d_in[4];
    const float* tvec      = (const float*)d_in[5];
    float* out = (float*)d_out;

    render_kernel<<<dim3(NB * 512), dim3(512), 0, stream>>>(
        positions, colors, opacities, scales, qvec, tvec, out);
}

// Round 9
// 22.107 us; speedup vs baseline: 1.9241x; 1.6234x over previous
//
#include <hip/hip_runtime.h>
#include <cmath>

// Problem constants (match the reference)
#define HH 256
#define WW 256
#define NG 1024
#define NB 2
#define NTILE 256            // tiles per batch (32x8 px)
static constexpr float FXc = 300.0f;
static constexpr float FYc = 300.0f;
static constexpr float CXc = 128.0f;
static constexpr float CYc = 128.0f;
static constexpr float EPSc = 1e-8f;
static constexpr float LOG2E = 1.4426950408889634f;

#if defined(__has_builtin)
#if __has_builtin(__builtin_amdgcn_exp2f)
#define FAST_EXP2(x) __builtin_amdgcn_exp2f(x)
#else
#define FAST_EXP2(x) exp2f(x)
#endif
#else
#define FAST_EXP2(x) exp2f(x)
#endif

// R6 render structure + deterministic per-tile culling.
//   prep  <<<NB,512>>>: project gaussians -> w0 (k,kx,ky,A), w1 (r,g,b,0),
//         cull (ux,uy,rcut,0); sentinel param at index NG (A=-500 -> w=0).
//   build <<<128,256>>>: one wave per (b,tile): ballot-scan over 1024
//         gaussians, keep g if its rcut-box overlaps the 32x8 tile;
//         g-order preserved (deterministic, no atomics); pad count to x8
//         with sentinel index NG.
//   render<<<NB*256,512>>>: stage the tile's list (gathered) into LDS,
//         then R6's quad loop over np/8 iterations (8-way split).
//   Cutoff: rcut = 7.8987*s  (k*rcut^2 = -45); worst-case culled error
//   <= 1024*2^-45/EPS ~ 0.003 < threshold even where den ~ 0.

__global__ __launch_bounds__(512) void prep_kernel(
    const float* __restrict__ positions, const float* __restrict__ colors,
    const float* __restrict__ opacities, const float* __restrict__ scales,
    const float* __restrict__ qvec, const float* __restrict__ tvec,
    float4* __restrict__ w0, float4* __restrict__ w1,
    float4* __restrict__ cull)
{
    const int b = blockIdx.x;
    float qw = qvec[b * 4 + 0], qx = qvec[b * 4 + 1];
    float qy = qvec[b * 4 + 2], qz = qvec[b * 4 + 3];
    float rin = rsqrtf(qw * qw + qx * qx + qy * qy + qz * qz);
    qw *= rin; qx *= rin; qy *= rin; qz *= rin;
    const float r00 = 1.0f - 2.0f * (qy * qy + qz * qz);
    const float r01 = 2.0f * (qx * qy - qz * qw);
    const float r02 = 2.0f * (qx * qz + qy * qw);
    const float r10 = 2.0f * (qx * qy + qz * qw);
    const float r11 = 1.0f - 2.0f * (qx * qx + qz * qz);
    const float r12 = 2.0f * (qy * qz - qx * qw);
    const float r20 = 2.0f * (qx * qz - qy * qw);
    const float r21 = 2.0f * (qy * qz + qx * qw);
    const float r22 = 1.0f - 2.0f * (qx * qx + qy * qy);
    const float t0 = tvec[b * 3 + 0], t1 = tvec[b * 3 + 1], t2 = tvec[b * 3 + 2];

    const int boff = b * (NG + 1);
    #pragma unroll
    for (int j = 0; j < NG / 512; ++j) {
        const int g = threadIdx.x + j * 512;
        const float X = positions[g * 3 + 0];
        const float Y = positions[g * 3 + 1];
        const float Z = positions[g * 3 + 2];
        const float cxp = r00 * X + r01 * Y + r02 * Z + t0;
        const float cyp = r10 * X + r11 * Y + r12 * Z + t1;
        const float czp = r20 * X + r21 * Y + r22 * Z + t2;
        const float iz = 1.0f / czp;
        const float ux = cxp * iz * FXc + CXc;
        const float uy = cyp * iz * FYc + CYc;
        const float s = scales[g];
        const float k = -0.5f * LOG2E / (s * s);
        const float lop = __log2f(opacities[g]);
        const float kx = -2.0f * k * ux;
        const float ky = -2.0f * k * uy;
        const float A = fmaf(k, fmaf(ux, ux, uy * uy), lop);
        w0[boff + g] = make_float4(k, kx, ky, A);
        w1[boff + g] = make_float4(colors[g * 3 + 0], colors[g * 3 + 1],
                                   colors[g * 3 + 2], 0.0f);
        cull[b * NG + g] = make_float4(ux, uy, 7.8987f * s, 0.0f);
    }
    if (threadIdx.x == 0) {   // zero-weight sentinel for list padding
        w0[boff + NG] = make_float4(0.0f, 0.0f, 0.0f, -500.0f);
        w1[boff + NG] = make_float4(0.0f, 0.0f, 0.0f, 0.0f);
    }
}

__global__ __launch_bounds__(256) void build_kernel(
    const float4* __restrict__ cull,
    unsigned short* __restrict__ lists,   // [NB*NTILE][NG]
    int* __restrict__ counts)             // [NB*NTILE]
{
    const int wave = blockIdx.x * 4 + (threadIdx.x >> 6);
    const int lane = threadIdx.x & 63;
    const int b = wave >> 8;              // NTILE = 256
    const int tile = wave & 255;
    const float cx = (float)((tile & 7) << 5) + 15.5f;
    const float cy = (float)((tile >> 3) << 3) + 3.5f;

    unsigned short* lp = lists + (size_t)wave * NG;
    int base = 0;
    #pragma unroll
    for (int r = 0; r < NG / 64; ++r) {
        const int g = r * 64 + lane;
        const float4 c = cull[b * NG + g];
        const bool in = (fabsf(c.x - cx) <= 15.5f + c.z) &&
                        (fabsf(c.y - cy) <= 3.5f + c.z);
        const unsigned long long m = __ballot(in);
        if (in) {
            const int pre = __popcll(m & ((1ull << lane) - 1ull));
            lp[base + pre] = (unsigned short)g;
        }
        base += __popcll(m);
    }
    const int np = (base + 7) & ~7;       // pad to multiple of 8
    if (lane < np - base) lp[base + lane] = (unsigned short)NG;
    if (lane == 0) counts[wave] = np;
}

__global__ __launch_bounds__(512) void render_kernel(
    const float4* __restrict__ w0, const float4* __restrict__ w1,
    const unsigned short* __restrict__ lists,
    const int* __restrict__ counts,
    float* __restrict__ out)              // [B,3,H,W]
{
    __shared__ float4 gs0[NG];
    __shared__ float4 gs1[NG];

    const int b = blockIdx.x >> 8;        // 256 blocks per batch
    int tile = blockIdx.x & 255;
    if (b) tile ^= 128;                   // decorrelate per-CU load across batches
    const int x0 = (tile & 7) << 5;       // 8 tiles of 32 px in x
    const int y0 = (tile >> 3) << 3;      // 32 tiles of 8 px in y

    const int wave = b * NTILE + tile;
    const int np = counts[wave];
    const unsigned short* lp = lists + (size_t)wave * NG;
    const int boff = b * (NG + 1);

    for (int j = threadIdx.x; j < np; j += 512) {
        const int idx = lp[j];
        gs0[j] = w0[boff + idx];
        gs1[j] = w1[boff + idx];
    }
    __syncthreads();

    const int h = threadIdx.x & 7;        // gaussian split lane
    const int t = threadIdx.x >> 3;       // quad id [0,64)
    const int px0i = x0 + ((t & 15) << 1);
    const int py0i = y0 + ((t >> 4) << 1);
    const float px = (float)px0i;
    const float py = (float)py0i;
    const float c2 = fmaf(px, px, py * py);
    const float u = fmaf(2.0f, px, 1.0f);
    const float v = fmaf(2.0f, py, 1.0f);

    float4 aden = make_float4(0.f, 0.f, 0.f, 0.f);
    float4 ar = aden, ag = aden, ab = aden;

    const int iters = np >> 3;
    #pragma unroll 4
    for (int i = 0; i < iters; ++i) {
        const int g = (i << 3) + h;
        const float4 g0 = gs0[g];
        const float4 g1 = gs1[g];
        const float k = g0.x;
        float e00 = fmaf(k, c2, g0.w);
        e00 = fmaf(g0.y, px, e00);
        e00 = fmaf(g0.z, py, e00);
        const float d10 = fminf(fmaf(k, u, g0.y), 126.0f);
        const float d01 = fminf(fmaf(k, v, g0.z), 126.0f);
        const float w00 = FAST_EXP2(e00);
        const float Ex = FAST_EXP2(d10);
        const float Ey = FAST_EXP2(d01);
        const float w10 = w00 * Ex;
        const float w01 = w00 * Ey;
        const float w11 = w10 * Ey;
        aden.x += w00; aden.y += w10; aden.z += w01; aden.w += w11;
        ar.x = fmaf(w00, g1.x, ar.x); ar.y = fmaf(w10, g1.x, ar.y);
        ar.z = fmaf(w01, g1.x, ar.z); ar.w = fmaf(w11, g1.x, ar.w);
        ag.x = fmaf(w00, g1.y, ag.x); ag.y = fmaf(w10, g1.y, ag.y);
        ag.z = fmaf(w01, g1.y, ag.z); ag.w = fmaf(w11, g1.y, ag.w);
        ab.x = fmaf(w00, g1.z, ab.x); ab.y = fmaf(w10, g1.z, ab.y);
        ab.z = fmaf(w01, g1.z, ab.z); ab.w = fmaf(w11, g1.z, ab.w);
    }

    #pragma unroll
    for (int m = 1; m <= 4; m <<= 1) {
        aden.x += __shfl_xor(aden.x, m); aden.y += __shfl_xor(aden.y, m);
        aden.z += __shfl_xor(aden.z, m); aden.w += __shfl_xor(aden.w, m);
        ar.x += __shfl_xor(ar.x, m); ar.y += __shfl_xor(ar.y, m);
        ar.z += __shfl_xor(ar.z, m); ar.w += __shfl_xor(ar.w, m);
        ag.x += __shfl_xor(ag.x, m); ag.y += __shfl_xor(ag.y, m);
        ag.z += __shfl_xor(ag.z, m); ag.w += __shfl_xor(ag.w, m);
        ab.x += __shfl_xor(ab.x, m); ab.y += __shfl_xor(ab.y, m);
        ab.z += __shfl_xor(ab.z, m); ab.w += __shfl_xor(ab.w, m);
    }

    if (h < 4) {
        float den, cr, cg, cb;
        if (h == 0)      { den = aden.x; cr = ar.x; cg = ag.x; cb = ab.x; }
        else if (h == 1) { den = aden.y; cr = ar.y; cg = ag.y; cb = ab.y; }
        else if (h == 2) { den = aden.z; cr = ar.z; cg = ag.z; cb = ab.z; }
        else             { den = aden.w; cr = ar.w; cg = ag.w; cb = ab.w; }
        const int pxx = px0i + (h & 1);
        const int pyy = py0i + (h >> 1);
        const float inv = 1.0f / (den + EPSc);
        const size_t o = (size_t)b * 3 * 65536 + (size_t)pyy * WW + pxx;
        out[o]           = cr * inv;
        out[o + 65536]   = cg * inv;
        out[o + 131072]  = cb * inv;
    }
}

extern "C" void kernel_launch(void* const* d_in, const int* in_sizes, int n_in,
                              void* d_out, int out_size, void* d_ws, size_t ws_size,
                              hipStream_t stream) {
    const float* positions = (const float*)d_in[0];
    const float* colors    = (const float*)d_in[1];
    const float* opacities = (const float*)d_in[2];
    const float* scales    = (const float*)d_in[3];
    const float* qvec      = (const float*)d_in[4];
    const float* tvec      = (const float*)d_in[5];
    float* out = (float*)d_out;

    // ws layout (all within ~1.2 MB; ws is ~256 MB per poison-fill size)
    float4* w0   = (float4*)d_ws;                       // NB*(NG+1)
    float4* w1   = w0 + NB * (NG + 1);                  // NB*(NG+1)
    float4* cull = w1 + NB * (NG + 1);                  // NB*NG
    unsigned short* lists = (unsigned short*)(cull + NB * NG);  // NB*NTILE*NG
    int* counts = (int*)(lists + (size_t)NB * NTILE * NG);      // NB*NTILE

    prep_kernel<<<dim3(NB), dim3(512), 0, stream>>>(
        positions, colors, opacities, scales, qvec, tvec, w0, w1, cull);
    build_kernel<<<dim3(NB * NTILE / 4), dim3(256), 0, stream>>>(
        cull, lists, counts);
    render_kernel<<<dim3(NB * NTILE), dim3(512), 0, stream>>>(
        w0, w1, lists, counts, out);
}

// Round 10
// 16.113 us; speedup vs baseline: 2.6399x; 1.3720x over previous
//
#include <hip/hip_runtime.h>
#include <cmath>

// Problem constants (match the reference)
#define HH 256
#define WW 256
#define NG 1024
#define NB 2
#define NTILE 256            // tiles per batch (32x8 px)
static constexpr float FXc = 300.0f;
static constexpr float FYc = 300.0f;
static constexpr float CXc = 128.0f;
static constexpr float CYc = 128.0f;
static constexpr float EPSc = 1e-8f;
static constexpr float LOG2E = 1.4426950408889634f;

#if defined(__has_builtin)
#if __has_builtin(__builtin_amdgcn_exp2f)
#define FAST_EXP2(x) __builtin_amdgcn_exp2f(x)
#else
#define FAST_EXP2(x) exp2f(x)
#endif
#else
#define FAST_EXP2(x) exp2f(x)
#endif

// Two-kernel structure (R9 + fusion + exact circle-rect cull):
//   setup <<<128,256>>>: each block projects all NG gaussians into LDS
//     (ux,uy,rcut); 4 waves ballot-scan 4 tiles (exact circle-rect
//     distance test); blocks (blockIdx&63)==0 also write w0/w1 once.
//     g-order preserved (deterministic); lists padded to x8 with
//     sentinel index NG (A=-500 -> w=0, k=0 -> Ex=Ey=1, no NaN).
//   render <<<NB*256,512>>>: unchanged R9 kernel: stage tile's list into
//     LDS, 2x2 quad per thread, 8-way gaussian split, shfl_xor combine.
//   Cutoff: rcut = 7.8987*s (k*rcut^2 = -45); worst-case culled error
//   <= 1024*2^-45/EPS ~ 0.003 < threshold. Circle-rect test only drops
//   gaussians already below the cutoff across the whole tile.

__global__ __launch_bounds__(256) void setup_kernel(
    const float* __restrict__ positions, const float* __restrict__ colors,
    const float* __restrict__ opacities, const float* __restrict__ scales,
    const float* __restrict__ qvec, const float* __restrict__ tvec,
    float4* __restrict__ w0, float4* __restrict__ w1,
    unsigned short* __restrict__ lists,   // [NB*NTILE][NG]
    int* __restrict__ counts)             // [NB*NTILE]
{
    __shared__ float4 cs[NG];             // (ux, uy, rcut, 0)

    const int b = blockIdx.x >> 6;        // 64 blocks per batch
    const int tg = (blockIdx.x & 63) << 2;    // first of this block's 4 tiles
    const bool writer = (blockIdx.x & 63) == 0;

    // --- wave-uniform rotation setup ---
    float qw = qvec[b * 4 + 0], qx = qvec[b * 4 + 1];
    float qy = qvec[b * 4 + 2], qz = qvec[b * 4 + 3];
    float rin = rsqrtf(qw * qw + qx * qx + qy * qy + qz * qz);
    qw *= rin; qx *= rin; qy *= rin; qz *= rin;
    const float r00 = 1.0f - 2.0f * (qy * qy + qz * qz);
    const float r01 = 2.0f * (qx * qy - qz * qw);
    const float r02 = 2.0f * (qx * qz + qy * qw);
    const float r10 = 2.0f * (qx * qy + qz * qw);
    const float r11 = 1.0f - 2.0f * (qx * qx + qz * qz);
    const float r12 = 2.0f * (qy * qz - qx * qw);
    const float r20 = 2.0f * (qx * qz - qy * qw);
    const float r21 = 2.0f * (qy * qz + qx * qw);
    const float r22 = 1.0f - 2.0f * (qx * qx + qy * qy);
    const float t0 = tvec[b * 3 + 0], t1 = tvec[b * 3 + 1], t2 = tvec[b * 3 + 2];

    const int boff = b * (NG + 1);
    #pragma unroll
    for (int j = 0; j < NG / 256; ++j) {
        const int g = threadIdx.x + j * 256;
        const float X = positions[g * 3 + 0];
        const float Y = positions[g * 3 + 1];
        const float Z = positions[g * 3 + 2];
        const float cxp = r00 * X + r01 * Y + r02 * Z + t0;
        const float cyp = r10 * X + r11 * Y + r12 * Z + t1;
        const float czp = r20 * X + r21 * Y + r22 * Z + t2;
        const float iz = 1.0f / czp;
        const float ux = cxp * iz * FXc + CXc;
        const float uy = cyp * iz * FYc + CYc;
        const float s = scales[g];
        cs[g] = make_float4(ux, uy, 7.8987f * s, 0.0f);
        if (writer) {
            const float k = -0.5f * LOG2E / (s * s);
            const float lop = __log2f(opacities[g]);
            const float kx = -2.0f * k * ux;
            const float ky = -2.0f * k * uy;
            const float A = fmaf(k, fmaf(ux, ux, uy * uy), lop);
            w0[boff + g] = make_float4(k, kx, ky, A);
            w1[boff + g] = make_float4(colors[g * 3 + 0], colors[g * 3 + 1],
                                       colors[g * 3 + 2], 0.0f);
        }
    }
    if (writer && threadIdx.x == 0) {     // zero-weight sentinel
        w0[boff + NG] = make_float4(0.0f, 0.0f, 0.0f, -500.0f);
        w1[boff + NG] = make_float4(0.0f, 0.0f, 0.0f, 0.0f);
    }
    __syncthreads();

    // --- one wave per tile: ballot-scan with exact circle-rect test ---
    const int wv = threadIdx.x >> 6;
    const int lane = threadIdx.x & 63;
    const int tile = tg + wv;
    const float cx = (float)((tile & 7) << 5) + 15.5f;
    const float cy = (float)((tile >> 3) << 3) + 3.5f;

    unsigned short* lp = lists + (size_t)(b * NTILE + tile) * NG;
    int base = 0;
    #pragma unroll
    for (int r = 0; r < NG / 64; ++r) {
        const int g = r * 64 + lane;
        const float4 c = cs[g];
        const float ddx = fmaxf(fabsf(c.x - cx) - 15.5f, 0.0f);
        const float ddy = fmaxf(fabsf(c.y - cy) - 3.5f, 0.0f);
        const bool in = fmaf(ddx, ddx, ddy * ddy) <= c.z * c.z;
        const unsigned long long m = __ballot(in);
        if (in) {
            const int pre = __popcll(m & ((1ull << lane) - 1ull));
            lp[base + pre] = (unsigned short)g;
        }
        base += __popcll(m);
    }
    const int np = (base + 7) & ~7;       // pad to multiple of 8
    if (lane < np - base) lp[base + lane] = (unsigned short)NG;
    if (lane == 0) counts[b * NTILE + tile] = np;
}

__global__ __launch_bounds__(512) void render_kernel(
    const float4* __restrict__ w0, const float4* __restrict__ w1,
    const unsigned short* __restrict__ lists,
    const int* __restrict__ counts,
    float* __restrict__ out)              // [B,3,H,W]
{
    __shared__ float4 gs0[NG];
    __shared__ float4 gs1[NG];

    const int b = blockIdx.x >> 8;        // 256 blocks per batch
    int tile = blockIdx.x & 255;
    if (b) tile ^= 128;                   // decorrelate per-CU load across batches
    const int x0 = (tile & 7) << 5;       // 8 tiles of 32 px in x
    const int y0 = (tile >> 3) << 3;      // 32 tiles of 8 px in y

    const int wave = b * NTILE + tile;
    const int np = counts[wave];
    const unsigned short* lp = lists + (size_t)wave * NG;
    const int boff = b * (NG + 1);

    for (int j = threadIdx.x; j < np; j += 512) {
        const int idx = lp[j];
        gs0[j] = w0[boff + idx];
        gs1[j] = w1[boff + idx];
    }
    __syncthreads();

    const int h = threadIdx.x & 7;        // gaussian split lane
    const int t = threadIdx.x >> 3;       // quad id [0,64)
    const int px0i = x0 + ((t & 15) << 1);
    const int py0i = y0 + ((t >> 4) << 1);
    const float px = (float)px0i;
    const float py = (float)py0i;
    const float c2 = fmaf(px, px, py * py);
    const float u = fmaf(2.0f, px, 1.0f);
    const float v = fmaf(2.0f, py, 1.0f);

    float4 aden = make_float4(0.f, 0.f, 0.f, 0.f);
    float4 ar = aden, ag = aden, ab = aden;

    const int iters = np >> 3;
    #pragma unroll 4
    for (int i = 0; i < iters; ++i) {
        const int g = (i << 3) + h;
        const float4 g0 = gs0[g];
        const float4 g1 = gs1[g];
        const float k = g0.x;
        float e00 = fmaf(k, c2, g0.w);
        e00 = fmaf(g0.y, px, e00);
        e00 = fmaf(g0.z, py, e00);
        const float d10 = fminf(fmaf(k, u, g0.y), 126.0f);
        const float d01 = fminf(fmaf(k, v, g0.z), 126.0f);
        const float w00 = FAST_EXP2(e00);
        const float Ex = FAST_EXP2(d10);
        const float Ey = FAST_EXP2(d01);
        const float w10 = w00 * Ex;
        const float w01 = w00 * Ey;
        const float w11 = w10 * Ey;
        aden.x += w00; aden.y += w10; aden.z += w01; aden.w += w11;
        ar.x = fmaf(w00, g1.x, ar.x); ar.y = fmaf(w10, g1.x, ar.y);
        ar.z = fmaf(w01, g1.x, ar.z); ar.w = fmaf(w11, g1.x, ar.w);
        ag.x = fmaf(w00, g1.y, ag.x); ag.y = fmaf(w10, g1.y, ag.y);
        ag.z = fmaf(w01, g1.y, ag.z); ag.w = fmaf(w11, g1.y, ag.w);
        ab.x = fmaf(w00, g1.z, ab.x); ab.y = fmaf(w10, g1.z, ab.y);
        ab.z = fmaf(w01, g1.z, ab.z); ab.w = fmaf(w11, g1.z, ab.w);
    }

    #pragma unroll
    for (int m = 1; m <= 4; m <<= 1) {
        aden.x += __shfl_xor(aden.x, m); aden.y += __shfl_xor(aden.y, m);
        aden.z += __shfl_xor(aden.z, m); aden.w += __shfl_xor(aden.w, m);
        ar.x += __shfl_xor(ar.x, m); ar.y += __shfl_xor(ar.y, m);
        ar.z += __shfl_xor(ar.z, m); ar.w += __shfl_xor(ar.w, m);
        ag.x += __shfl_xor(ag.x, m); ag.y += __shfl_xor(ag.y, m);
        ag.z += __shfl_xor(ag.z, m); ag.w += __shfl_xor(ag.w, m);
        ab.x += __shfl_xor(ab.x, m); ab.y += __shfl_xor(ab.y, m);
        ab.z += __shfl_xor(ab.z, m); ab.w += __shfl_xor(ab.w, m);
    }

    if (h < 4) {
        float den, cr, cg, cb;
        if (h == 0)      { den = aden.x; cr = ar.x; cg = ag.x; cb = ab.x; }
        else if (h == 1) { den = aden.y; cr = ar.y; cg = ag.y; cb = ab.y; }
        else if (h == 2) { den = aden.z; cr = ar.z; cg = ag.z; cb = ab.z; }
        else             { den = aden.w; cr = ar.w; cg = ag.w; cb = ab.w; }
        const int pxx = px0i + (h & 1);
        const int pyy = py0i + (h >> 1);
        const float inv = 1.0f / (den + EPSc);
        const size_t o = (size_t)b * 3 * 65536 + (size_t)pyy * WW + pxx;
        out[o]           = cr * inv;
        out[o + 65536]   = cg * inv;
        out[o + 131072]  = cb * inv;
    }
}

extern "C" void kernel_launch(void* const* d_in, const int* in_sizes, int n_in,
                              void* d_out, int out_size, void* d_ws, size_t ws_size,
                              hipStream_t stream) {
    const float* positions = (const float*)d_in[0];
    const float* colors    = (const float*)d_in[1];
    const float* opacities = (const float*)d_in[2];
    const float* scales    = (const float*)d_in[3];
    const float* qvec      = (const float*)d_in[4];
    const float* tvec      = (const float*)d_in[5];
    float* out = (float*)d_out;

    // ws layout (~1.1 MB total; ws is ~256 MB)
    float4* w0 = (float4*)d_ws;                                 // NB*(NG+1)
    float4* w1 = w0 + NB * (NG + 1);                            // NB*(NG+1)
    unsigned short* lists = (unsigned short*)(w1 + NB * (NG + 1)); // NB*NTILE*NG
    int* counts = (int*)(lists + (size_t)NB * NTILE * NG);      // NB*NTILE

    setup_kernel<<<dim3(NB * 64), dim3(256), 0, stream>>>(
        positions, colors, opacities, scales, qvec, tvec, w0, w1, lists, counts);
    render_kernel<<<dim3(NB * NTILE), dim3(512), 0, stream>>>(
        w0, w1, lists, counts, out);
}

// Round 11
// 12.241 us; speedup vs baseline: 3.4749x; 1.3163x over previous
//
#include <hip/hip_runtime.h>
#include <cmath>

// Problem constants (match the reference)
#define HH 256
#define WW 256
#define NG 1024
#define NB 2
#define NTILE 256            // tiles per batch (32x8 px)
static constexpr float FXc = 300.0f;
static constexpr float FYc = 300.0f;
static constexpr float CXc = 128.0f;
static constexpr float CYc = 128.0f;
static constexpr float EPSc = 1e-8f;
static constexpr float LOG2E = 1.4426950408889634f;

#if defined(__has_builtin)
#if __has_builtin(__builtin_amdgcn_exp2f)
#define FAST_EXP2(x) __builtin_amdgcn_exp2f(x)
#else
#define FAST_EXP2(x) exp2f(x)
#endif
#else
#define FAST_EXP2(x) exp2f(x)
#endif

// SINGLE fused kernel (R10 render + in-block cull):
//   grid = 512 blocks (NB*NTILE), 512 threads (8 waves), 32x8-px tile.
//   Phase 1 (cull+stage): wave w projects gaussians [w*128,(w+1)*128) in
//     2 rounds of 64; exact circle-rect test (rcut = 7.8987*s, i.e.
//     k*rcut^2 = -45); ballot + intra-wave prefix gives deterministic
//     g-ascending compaction; kept params buffered in named registers,
//     written to LDS after an 8-way wave-count prefix (no atomics).
//     List padded to x8 with sentinel (k=kx=ky=0, A=-500 -> w=0, Ex=Ey=1).
//   Phase 2 (render): R10's loop byte-for-byte: thread = (quad t, h),
//     2x2 pixel quad, 8-way gaussian split, 3 exp + 3 mul per
//     gaussian-quad, step deltas clamped <=126 (no 0*inf), shfl_xor
//     combine, lanes h<4 write the quad's pixels.
//   Error bound: culled total <= 1024*2^-45 < EPS*0.003 -> absmax
//     contribution <= ~0.003 even where den ~ EPS.
__global__ __launch_bounds__(512) void render_kernel(
    const float* __restrict__ positions,   // [N,3]
    const float* __restrict__ colors,      // [N,3]
    const float* __restrict__ opacities,   // [N,1]
    const float* __restrict__ scales,      // [N,1]
    const float* __restrict__ qvec,        // [B,4]
    const float* __restrict__ tvec,        // [B,3]
    float* __restrict__ out)               // [B,3,H,W]
{
    __shared__ float4 gs0[NG];  // (k, kx, ky, A)
    __shared__ float4 gs1[NG];  // (r, g, b, 0)
    __shared__ int wcnt[8];

    const int b = blockIdx.x >> 8;        // 256 blocks per batch
    int tile = blockIdx.x & 255;
    if (b) tile ^= 128;                   // decorrelate per-CU load across batches
    const int x0 = (tile & 7) << 5;       // 8 tiles of 32 px in x
    const int y0 = (tile >> 3) << 3;      // 32 tiles of 8 px in y
    const float cx = (float)x0 + 15.5f;
    const float cy = (float)y0 + 3.5f;

    // --- wave-uniform rotation setup ---
    float qw = qvec[b * 4 + 0], qx = qvec[b * 4 + 1];
    float qy = qvec[b * 4 + 2], qz = qvec[b * 4 + 3];
    float rin = rsqrtf(qw * qw + qx * qx + qy * qy + qz * qz);
    qw *= rin; qx *= rin; qy *= rin; qz *= rin;
    const float r00 = 1.0f - 2.0f * (qy * qy + qz * qz);
    const float r01 = 2.0f * (qx * qy - qz * qw);
    const float r02 = 2.0f * (qx * qz + qy * qw);
    const float r10 = 2.0f * (qx * qy + qz * qw);
    const float r11 = 1.0f - 2.0f * (qx * qx + qz * qz);
    const float r12 = 2.0f * (qy * qz - qx * qw);
    const float r20 = 2.0f * (qx * qz - qy * qw);
    const float r21 = 2.0f * (qy * qz + qx * qw);
    const float r22 = 1.0f - 2.0f * (qx * qx + qy * qy);
    const float t0 = tvec[b * 3 + 0], t1 = tvec[b * 3 + 1], t2 = tvec[b * 3 + 2];

    // --- phase 1: project + cull + deterministic compaction ---
    const int wv = threadIdx.x >> 6;      // wave id [0,8)
    const int lane = threadIdx.x & 63;

    float4 pa0, pa1, pc0, pc1;            // buffered kept params (named: rule #20)
    int pos0 = -1, pos1 = -1;
    int cnt = 0;                          // wave-local running count

    #pragma unroll
    for (int r = 0; r < 2; ++r) {
        const int g = wv * 128 + r * 64 + lane;
        const float X = positions[g * 3 + 0];
        const float Y = positions[g * 3 + 1];
        const float Z = positions[g * 3 + 2];
        const float cxp = r00 * X + r01 * Y + r02 * Z + t0;
        const float cyp = r10 * X + r11 * Y + r12 * Z + t1;
        const float czp = r20 * X + r21 * Y + r22 * Z + t2;
        const float iz = 1.0f / czp;
        const float ux = cxp * iz * FXc + CXc;
        const float uy = cyp * iz * FYc + CYc;
        const float s = scales[g];
        const float rcut = 7.8987f * s;
        const float ddx = fmaxf(fabsf(ux - cx) - 15.5f, 0.0f);
        const float ddy = fmaxf(fabsf(uy - cy) - 3.5f, 0.0f);
        const bool in = fmaf(ddx, ddx, ddy * ddy) <= rcut * rcut;
        const unsigned long long m = __ballot(in);
        if (in) {
            const float k = -0.5f * LOG2E / (s * s);
            const float lop = __log2f(opacities[g]);
            const float kx = -2.0f * k * ux;
            const float ky = -2.0f * k * uy;
            const float A = fmaf(k, fmaf(ux, ux, uy * uy), lop);
            const int pre = cnt + __popcll(m & ((1ull << lane) - 1ull));
            if (r == 0) {
                pa0 = make_float4(k, kx, ky, A);
                pc0 = make_float4(colors[g * 3 + 0], colors[g * 3 + 1],
                                  colors[g * 3 + 2], 0.0f);
                pos0 = pre;
            } else {
                pa1 = make_float4(k, kx, ky, A);
                pc1 = make_float4(colors[g * 3 + 0], colors[g * 3 + 1],
                                  colors[g * 3 + 2], 0.0f);
                pos1 = pre;
            }
        }
        cnt += __popcll(m);
    }
    if (lane == 0) wcnt[wv] = cnt;
    __syncthreads();

    int base = 0, npTot = 0;
    #pragma unroll
    for (int j = 0; j < 8; ++j) {
        const int c = wcnt[j];
        if (j < wv) base += c;
        npTot += c;
    }
    if (pos0 >= 0) { gs0[base + pos0] = pa0; gs1[base + pos0] = pc0; }
    if (pos1 >= 0) { gs0[base + pos1] = pa1; gs1[base + pos1] = pc1; }
    const int np = (npTot + 7) & ~7;      // pad to multiple of 8
    if ((int)threadIdx.x < np - npTot) {  // sentinel: w=0, Ex=Ey=1
        gs0[npTot + threadIdx.x] = make_float4(0.0f, 0.0f, 0.0f, -500.0f);
        gs1[npTot + threadIdx.x] = make_float4(0.0f, 0.0f, 0.0f, 0.0f);
    }
    __syncthreads();

    // --- phase 2: render (unchanged R10 loop) ---
    const int h = threadIdx.x & 7;        // gaussian split lane
    const int t = threadIdx.x >> 3;       // quad id [0,64)
    const int px0i = x0 + ((t & 15) << 1);
    const int py0i = y0 + ((t >> 4) << 1);
    const float px = (float)px0i;
    const float py = (float)py0i;
    const float c2 = fmaf(px, px, py * py);
    const float u = fmaf(2.0f, px, 1.0f);
    const float v = fmaf(2.0f, py, 1.0f);

    float4 aden = make_float4(0.f, 0.f, 0.f, 0.f);
    float4 ar = aden, ag = aden, ab = aden;

    const int iters = np >> 3;
    #pragma unroll 4
    for (int i = 0; i < iters; ++i) {
        const int g = (i << 3) + h;
        const float4 g0 = gs0[g];
        const float4 g1 = gs1[g];
        const float k = g0.x;
        float e00 = fmaf(k, c2, g0.w);
        e00 = fmaf(g0.y, px, e00);
        e00 = fmaf(g0.z, py, e00);
        const float d10 = fminf(fmaf(k, u, g0.y), 126.0f);
        const float d01 = fminf(fmaf(k, v, g0.z), 126.0f);
        const float w00 = FAST_EXP2(e00);
        const float Ex = FAST_EXP2(d10);
        const float Ey = FAST_EXP2(d01);
        const float w10 = w00 * Ex;
        const float w01 = w00 * Ey;
        const float w11 = w10 * Ey;
        aden.x += w00; aden.y += w10; aden.z += w01; aden.w += w11;
        ar.x = fmaf(w00, g1.x, ar.x); ar.y = fmaf(w10, g1.x, ar.y);
        ar.z = fmaf(w01, g1.x, ar.z); ar.w = fmaf(w11, g1.x, ar.w);
        ag.x = fmaf(w00, g1.y, ag.x); ag.y = fmaf(w10, g1.y, ag.y);
        ag.z = fmaf(w01, g1.y, ag.z); ag.w = fmaf(w11, g1.y, ag.w);
        ab.x = fmaf(w00, g1.z, ab.x); ab.y = fmaf(w10, g1.z, ab.y);
        ab.z = fmaf(w01, g1.z, ab.z); ab.w = fmaf(w11, g1.z, ab.w);
    }

    #pragma unroll
    for (int m = 1; m <= 4; m <<= 1) {
        aden.x += __shfl_xor(aden.x, m); aden.y += __shfl_xor(aden.y, m);
        aden.z += __shfl_xor(aden.z, m); aden.w += __shfl_xor(aden.w, m);
        ar.x += __shfl_xor(ar.x, m); ar.y += __shfl_xor(ar.y, m);
        ar.z += __shfl_xor(ar.z, m); ar.w += __shfl_xor(ar.w, m);
        ag.x += __shfl_xor(ag.x, m); ag.y += __shfl_xor(ag.y, m);
        ag.z += __shfl_xor(ag.z, m); ag.w += __shfl_xor(ag.w, m);
        ab.x += __shfl_xor(ab.x, m); ab.y += __shfl_xor(ab.y, m);
        ab.z += __shfl_xor(ab.z, m); ab.w += __shfl_xor(ab.w, m);
    }

    if (h < 4) {
        float den, cr, cg, cb;
        if (h == 0)      { den = aden.x; cr = ar.x; cg = ag.x; cb = ab.x; }
        else if (h == 1) { den = aden.y; cr = ar.y; cg = ag.y; cb = ab.y; }
        else if (h == 2) { den = aden.z; cr = ar.z; cg = ag.z; cb = ab.z; }
        else             { den = aden.w; cr = ar.w; cg = ag.w; cb = ab.w; }
        const int pxx = px0i + (h & 1);
        const int pyy = py0i + (h >> 1);
        const float inv = 1.0f / (den + EPSc);
        const size_t o = (size_t)b * 3 * 65536 + (size_t)pyy * WW + pxx;
        out[o]           = cr * inv;
        out[o + 65536]   = cg * inv;
        out[o + 131072]  = cb * inv;
    }
}

extern "C" void kernel_launch(void* const* d_in, const int* in_sizes, int n_in,
                              void* d_out, int out_size, void* d_ws, size_t ws_size,
                              hipStream_t stream) {
    const float* positions = (const float*)d_in[0];
    const float* colors    = (const float*)d_in[1];
    const float* opacities = (const float*)d_in[2];
    const float* scales    = (const float*)d_in[3];
    const float* qvec      = (const float*)d_in[4];
    const float* tvec      = (const float*)d_in[5];
    float* out = (float*)d_out;

    render_kernel<<<dim3(NB * NTILE), dim3(512), 0, stream>>>(
        positions, colors, opacities, scales, qvec, tvec, out);
}